// Round 8
// baseline (3710.022 us; speedup 1.0000x reference)
//
#include <hip/hip_runtime.h>

// LSTM decoder B=64,S=512,D=512,H=512,L=2 — Round 8: persistent kernel,
// SELF-VALIDATING h exchange: each h value stored as u32 (epoch<<16 | bf16)
// via sc1 (L3). Consumers spin on the data words themselves (tag equality)
// — no flags, no fences, no store-drain on the critical path.
// Anti-dep (buffer overwrite, 8-deep) via coarse progress flags every 4 steps.
// Roles: blocks 0..127 = layer0 step i, 128..255 = layer1 step i-1.

#define NB 64
#define NS 512
#define ND 512
#define NH 512

typedef __attribute__((ext_vector_type(8))) short short8;
typedef __attribute__((ext_vector_type(4))) float f32x4;
typedef unsigned long long ull;

// ---- ws layout (bytes) ----
#define WPK_OFF   0                  // 8,388,608
#define HT0_OFF   8388608            // 8 bufs * 32768 u32 = 1,048,576
#define HT1_OFF   9437184            // 1,048,576
#define FLAGS_OFF 10485760           // 256 u32
#define WPK_ELEMS_PER_ROLE (128 * 32 * 512)
#define TAGMASK 0xFFFF0000FFFF0000ULL

__device__ __forceinline__ unsigned int pack2bf(float a, float b) {
    unsigned int ua = __builtin_bit_cast(unsigned int, a);
    unsigned int ub = __builtin_bit_cast(unsigned int, b);
    ua += 0x7fffu + ((ua >> 16) & 1u);   // RNE
    ub += 0x7fffu + ((ub >> 16) & 1u);
    return (ua >> 16) | (ub & 0xffff0000u);
}
__device__ __forceinline__ unsigned short bf16r(float a) {
    unsigned int ua = __builtin_bit_cast(unsigned int, a);
    ua += 0x7fffu + ((ua >> 16) & 1u);
    return (unsigned short)(ua >> 16);
}

// L3-coherent primitives (relaxed agent atomics -> sc0 sc1, no cache maint.)
__device__ __forceinline__ ull ld_h64(const ull* p) {
    return __hip_atomic_load(p, __ATOMIC_RELAXED, __HIP_MEMORY_SCOPE_AGENT);
}
__device__ __forceinline__ void st_h32(unsigned int* p, unsigned int v) {
    __hip_atomic_store(p, v, __ATOMIC_RELAXED, __HIP_MEMORY_SCOPE_AGENT);
}
__device__ __forceinline__ unsigned int ld_flag(const unsigned int* p) {
    return __hip_atomic_load(p, __ATOMIC_RELAXED, __HIP_MEMORY_SCOPE_AGENT);
}
__device__ __forceinline__ void st_flag(unsigned int* p, unsigned int v) {
    __hip_atomic_store(p, v, __ATOMIC_RELAXED, __HIP_MEMORY_SCOPE_AGENT);
}

__device__ __forceinline__ bool tags_ok(const ull w[4], ull T) {
    return ((((w[0] ^ T) | (w[1] ^ T)) | ((w[2] ^ T) | (w[3] ^ T))) & TAGMASK) == 0ULL;
}
__device__ __forceinline__ unsigned int pack_lo(ull w) {
    return (unsigned int)(w & 0xFFFFULL) | (((unsigned int)(w >> 32) & 0xFFFFu) << 16);
}

// Repack weights into MFMA B-fragment order:
// fragment (r, nt, k0i), lane l, elem j: B[k][n], n = nt*16+(l&15), k = k0i*32+(l>>4)*8+j
__global__ void prep_weights_k(const float* __restrict__ W_ih,
                               const float* __restrict__ W_hh,
                               unsigned int* __restrict__ wpk_u32) {
    long long gid = (long long)blockIdx.x * blockDim.x + threadIdx.x; // 524288
    int l   = (int)(gid & 63);
    int k0i = (int)((gid >> 6) & 31);
    int nt  = (int)((gid >> 11) & 127);
    int r   = (int)(gid >> 18);
    int n = nt * 16 + (l & 15);
    int k = k0i * 32 + ((l >> 4) << 3);
    const float* src;
    if (k < 512) src = W_ih + ((long long)r * 2048 + n) * 512 + k;
    else         src = W_hh + ((long long)r * 2048 + n) * 512 + (k - 512);
    uint4 v;
    v.x = pack2bf(src[0], src[1]);
    v.y = pack2bf(src[2], src[3]);
    v.z = pack2bf(src[4], src[5]);
    v.w = pack2bf(src[6], src[7]);
    ((uint4*)wpk_u32)[gid] = v;
}

// Clear ALL tagged buffers (kills stale/garbage tags), write h_{-1} (tag 0)
// into buf 7 of both arrays, zero progress flags.
__global__ void prep_state_k(const float* __restrict__ eh,
                             unsigned int* __restrict__ ht0,
                             unsigned int* __restrict__ ht1,
                             unsigned int* __restrict__ flags) {
    int gid = blockIdx.x * blockDim.x + threadIdx.x;  // 262144
    if (gid < 262144) {
        int buf = gid >> 15, idx = gid & 32767;
        unsigned int v = (buf == 7) ? (unsigned int)bf16r(eh[idx]) : 0u;
        ht0[gid] = v;
        ht1[gid] = v;
    }
    if (gid < 256) flags[gid] = 0;
}

__global__ __launch_bounds__(256, 2)
void lstm_persist_k(const float* __restrict__ input,
                    const float* __restrict__ enc_c,
                    const float* __restrict__ b_ih,
                    const float* __restrict__ b_hh,
                    const unsigned short* __restrict__ wpk,
                    unsigned int* __restrict__ ht0,
                    unsigned int* __restrict__ ht1,
                    float* __restrict__ out,
                    unsigned int* __restrict__ flags) {
    __shared__ alignas(16) unsigned char smem[32768];
    const int bid  = blockIdx.x;
    const int role = bid >> 7;             // 0: layer0(i), 1: layer1(i-1)
    const int lb   = bid & 127;
    const int ms   = lb >> 5;              // batch block 0..3 (sync group)
    const int us   = lb & 31;              // unit block 0..31
    const int m0   = ms << 4;
    const int tid  = threadIdx.x;
    const int lane = tid & 63;
    const int tq   = tid >> 6;
    const int g    = __builtin_amdgcn_readfirstlane(tq);  // wave = gate

    const unsigned short* wp = wpk + (long long)role * WPK_ELEMS_PER_ROLE
                                   + (long long)(g * 32 + us) * (32 * 512);
    unsigned int* myflag   = flags + (ms << 6) + (role << 5) + us;
    const unsigned int* gf = flags + (ms << 6) + lane;

    // ---- per-thread cell state + biases (plain cached loads, once) ----
    const int m_l = tid >> 4, u_l = tid & 15;
    const int bcell = m0 + m_l;
    const int ucell = us * 16 + u_l;
    float cReg = enc_c[bcell * NH + ucell];
    const long long br = (long long)role * 2048;
    const float bias_i = b_ih[br + 0 * 512 + ucell] + b_hh[br + 0 * 512 + ucell];
    const float bias_f = b_ih[br + 1 * 512 + ucell] + b_hh[br + 1 * 512 + ucell];
    const float bias_g = b_ih[br + 2 * 512 + ucell] + b_hh[br + 2 * 512 + ucell];
    const float bias_o = b_ih[br + 3 * 512 + ucell] + b_hh[br + 3 * 512 + ucell];

    // ---- role0: prefetch x(0) into registers ----
    float4 xp[8];
    if (role == 0) {
        #pragma unroll
        for (int ii = 0; ii < 4; ++ii) {
            int k0i = ii * 4 + tq;
            const float* s = input + (long long)(m0 + (lane & 15)) * (NS * ND)
                                   + k0i * 32 + ((lane >> 4) << 3);
            xp[2 * ii]     = *(const float4*)s;
            xp[2 * ii + 1] = *(const float4*)(s + 4);
        }
    }

    for (int i = 0; i <= NS; ++i) {
        const bool active = (role == 0) ? (i < NS) : (i >= 1);

        // ---- anti-dep gate: every 4 steps, require all peers' progress ----
        if ((i & 3) == 0 && i >= 4) {
            if (tid < 64) {
                int need = i - 3;
                for (;;) {
                    unsigned int v = ld_flag(gf);
                    if (__ballot((int)v >= need) == 0xFFFFFFFFFFFFFFFFULL) break;
                    __builtin_amdgcn_s_sleep(1);
                }
            }
        }

        if (active) {
            const int m  = m0 + (lane & 15);
            const int kk = (lane >> 4) << 3;

            // ---- stage A (16 rows x K=1024 bf16, fragment-packed) ----
            if (role == 0) {
                // x-part from prefetched regs (ii 0..3)
                #pragma unroll
                for (int ii = 0; ii < 4; ++ii) {
                    int sid = ii * 256 + tid;
                    float4 lo = xp[2 * ii], hi = xp[2 * ii + 1];
                    uint4 val;
                    val.x = pack2bf(lo.x, lo.y);
                    val.y = pack2bf(lo.z, lo.w);
                    val.z = pack2bf(hi.x, hi.y);
                    val.w = pack2bf(hi.z, hi.w);
                    *(uint4*)(smem + sid * 16) = val;
                }
                // h-part = h0_{i-1}, tagged (ii 4..7)
                const unsigned int* h0p = ht0 + (((i - 1) & 7) << 15);
                ull T = (ull)i * 0x0001000000010000ULL;
                ull wa[4][4];
                const ull* pp[4];
                #pragma unroll
                for (int jj = 0; jj < 4; ++jj) {
                    int k0i = (4 + jj) * 4 + tq;               // 16..31
                    int kb  = (k0i - 16) * 32 + kk;
                    pp[jj] = (const ull*)(h0p + m * 512 + kb);
                    #pragma unroll
                    for (int q = 0; q < 4; ++q) wa[jj][q] = ld_h64(pp[jj] + q);
                }
                #pragma unroll
                for (int jj = 0; jj < 4; ++jj) {
                    while (!tags_ok(wa[jj], T)) {
                        #pragma unroll
                        for (int q = 0; q < 4; ++q) wa[jj][q] = ld_h64(pp[jj] + q);
                    }
                    uint4 val;
                    val.x = pack_lo(wa[jj][0]);
                    val.y = pack_lo(wa[jj][1]);
                    val.z = pack_lo(wa[jj][2]);
                    val.w = pack_lo(wa[jj][3]);
                    *(uint4*)(smem + ((4 + jj) * 256 + tid) * 16) = val;
                }
            } else {
                // x-part = h0_{i-1} tagged (ii 0..3); h-part = h1_{i-2} tagged (ii 4..7)
                const unsigned int* h0p = ht0 + (((i - 1) & 7) << 15);
                const unsigned int* h1p = ht1 + (((i - 2) & 7) << 15);
                ull Tx = (ull)i * 0x0001000000010000ULL;
                ull Th = (ull)(i - 1) * 0x0001000000010000ULL;
                ull wa[4][4], wb[4][4];
                const ull* pa[4];
                const ull* pb[4];
                #pragma unroll
                for (int jj = 0; jj < 4; ++jj) {
                    int k0ix = jj * 4 + tq;                    // 0..15
                    pa[jj] = (const ull*)(h0p + m * 512 + k0ix * 32 + kk);
                    #pragma unroll
                    for (int q = 0; q < 4; ++q) wa[jj][q] = ld_h64(pa[jj] + q);
                }
                #pragma unroll
                for (int jj = 0; jj < 4; ++jj) {
                    int k0ih = jj * 4 + tq;                    // (k0i-16) = 0..15
                    pb[jj] = (const ull*)(h1p + m * 512 + k0ih * 32 + kk);
                    #pragma unroll
                    for (int q = 0; q < 4; ++q) wb[jj][q] = ld_h64(pb[jj] + q);
                }
                #pragma unroll
                for (int jj = 0; jj < 4; ++jj) {
                    while (!tags_ok(wa[jj], Tx)) {
                        #pragma unroll
                        for (int q = 0; q < 4; ++q) wa[jj][q] = ld_h64(pa[jj] + q);
                    }
                    uint4 val;
                    val.x = pack_lo(wa[jj][0]);
                    val.y = pack_lo(wa[jj][1]);
                    val.z = pack_lo(wa[jj][2]);
                    val.w = pack_lo(wa[jj][3]);
                    *(uint4*)(smem + (jj * 256 + tid) * 16) = val;
                }
                #pragma unroll
                for (int jj = 0; jj < 4; ++jj) {
                    while (!tags_ok(wb[jj], Th)) {
                        #pragma unroll
                        for (int q = 0; q < 4; ++q) wb[jj][q] = ld_h64(pb[jj] + q);
                    }
                    uint4 val;
                    val.x = pack_lo(wb[jj][0]);
                    val.y = pack_lo(wb[jj][1]);
                    val.z = pack_lo(wb[jj][2]);
                    val.w = pack_lo(wb[jj][3]);
                    *(uint4*)(smem + ((4 + jj) * 256 + tid) * 16) = val;
                }
            }
            __syncthreads();                 // A staged; loads drained

            if (tid == 0) st_flag(myflag, (unsigned int)(i + 1));  // progress

            // ---- role0: prefetch x(i+1); latency hides under GEMM ----
            if (role == 0 && i + 1 < NS) {
                #pragma unroll
                for (int ii = 0; ii < 4; ++ii) {
                    int k0i = ii * 4 + tq;
                    const float* s = input + (long long)(m0 + (lane & 15)) * (NS * ND)
                                           + (long long)(i + 1) * ND
                                           + k0i * 32 + ((lane >> 4) << 3);
                    xp[2 * ii]     = *(const float4*)s;
                    xp[2 * ii + 1] = *(const float4*)(s + 4);
                }
            }

            // ---- GEMM: 32 MFMAs, 4 acc chains; weights from warm local L2 ----
            f32x4 acc0 = {0.f,0.f,0.f,0.f}, acc1 = {0.f,0.f,0.f,0.f};
            f32x4 acc2 = {0.f,0.f,0.f,0.f}, acc3 = {0.f,0.f,0.f,0.f};
            #pragma unroll
            for (int k0i = 0; k0i < 32; k0i += 4) {
                short8 a0 = *(const short8*)(smem + (k0i + 0) * 1024 + lane * 16);
                short8 a1 = *(const short8*)(smem + (k0i + 1) * 1024 + lane * 16);
                short8 a2 = *(const short8*)(smem + (k0i + 2) * 1024 + lane * 16);
                short8 a3 = *(const short8*)(smem + (k0i + 3) * 1024 + lane * 16);
                short8 b0 = *(const short8*)(wp + (k0i + 0) * 512 + lane * 8);
                short8 b1 = *(const short8*)(wp + (k0i + 1) * 512 + lane * 8);
                short8 b2 = *(const short8*)(wp + (k0i + 2) * 512 + lane * 8);
                short8 b3 = *(const short8*)(wp + (k0i + 3) * 512 + lane * 8);
                acc0 = __builtin_amdgcn_mfma_f32_16x16x32_bf16(a0, b0, acc0, 0, 0, 0);
                acc1 = __builtin_amdgcn_mfma_f32_16x16x32_bf16(a1, b1, acc1, 0, 0, 0);
                acc2 = __builtin_amdgcn_mfma_f32_16x16x32_bf16(a2, b2, acc2, 0, 0, 0);
                acc3 = __builtin_amdgcn_mfma_f32_16x16x32_bf16(a3, b3, acc3, 0, 0, 0);
            }
            f32x4 accS = (acc0 + acc1) + (acc2 + acc3);
            __syncthreads();   // done reading A; reuse smem for gates

            float (*Gs)[16][17] = (float (*)[16][17])smem;
            {
                int u_g  = lane & 15;
                int mrow = (lane >> 4) * 4;
                #pragma unroll
                for (int r = 0; r < 4; ++r)
                    Gs[g][mrow + r][u_g] = accS[r];
            }
            __syncthreads();

            // ---- fused LSTM cell (1 cell/thread, c stays in register) ----
            {
                float gi = Gs[0][m_l][u_l] + bias_i;
                float gf = Gs[1][m_l][u_l] + bias_f;
                float gg = Gs[2][m_l][u_l] + bias_g;
                float go = Gs[3][m_l][u_l] + bias_o;
                float ii = 1.f / (1.f + expf(-gi));
                float ff = 1.f / (1.f + expf(-gf));
                float gv = tanhf(gg);
                float oo = 1.f / (1.f + expf(-go));
                cReg = ff * cReg + ii * gv;
                float hn = oo * tanhf(cReg);
                unsigned short hb = bf16r(hn);

                // publish tagged h word (sc1) — the store IS the release
                if (role == 0) {
                    unsigned int* hbuf = ht0 + ((i & 7) << 15);
                    st_h32(hbuf + bcell * 512 + ucell,
                           ((unsigned int)(i + 1) << 16) | hb);
                } else {
                    unsigned int* hbuf = ht1 + (((i - 1) & 7) << 15);
                    st_h32(hbuf + bcell * 512 + ucell,
                           ((unsigned int)i << 16) | hb);
                    int s = i - 1;
                    out[(long long)bcell * (NS * NH) + (long long)s * NH + ucell] = hn;
                    if (i == NS) {
                        float* dst = out + (long long)NB * NS * NH;
                        dst[bcell * NH + ucell] = hn;
                        dst[NB * NH + bcell * NH + ucell] = cReg;
                    }
                }
            }
        } else {
            if (tid == 0) st_flag(myflag, (unsigned int)(i + 1));  // progress
        }

        __syncthreads();   // separate cell-phase Gs reads from next A-stage
    }
}

extern "C" void kernel_launch(void* const* d_in, const int* in_sizes, int n_in,
                              void* d_out, int out_size, void* d_ws, size_t ws_size,
                              hipStream_t stream) {
    const float* input = (const float*)d_in[0];
    const float* enc_h = (const float*)d_in[1];
    const float* enc_c = (const float*)d_in[2];
    const float* W_ih  = (const float*)d_in[3];
    const float* W_hh  = (const float*)d_in[4];
    const float* b_ih  = (const float*)d_in[5];
    const float* b_hh  = (const float*)d_in[6];
    float* out = (float*)d_out;
    unsigned char* ws = (unsigned char*)d_ws;

    unsigned short* wpk   = (unsigned short*)(ws + WPK_OFF);
    unsigned int*   ht0   = (unsigned int*)(ws + HT0_OFF);
    unsigned int*   ht1   = (unsigned int*)(ws + HT1_OFF);
    unsigned int*   flags = (unsigned int*)(ws + FLAGS_OFF);

    prep_weights_k<<<2048, 256, 0, stream>>>(W_ih, W_hh, (unsigned int*)wpk);
    prep_state_k<<<1024, 256, 0, stream>>>(enc_h, ht0, ht1, flags);
    lstm_persist_k<<<256, 256, 0, stream>>>(input, enc_c, b_ih, b_hh, wpk,
                                            ht0, ht1, out, flags);
}